// Round 2
// baseline (1352.118 us; speedup 1.0000x reference)
//
#include <hip/hip_runtime.h>

#define N_NODES 100000
#define N_EDGES 1600000
#define IN_DIM  128
#define HIDDEN  128
#define OUT_DIM 64

#define BUCK_SHIFT 6                          // 64-node buckets
#define BUCK_SZ    64
#define NB_BUCK ((N_NODES + BUCK_SZ - 1) / BUCK_SZ)   // 1563 buckets
#define EPB 4096                              // edges per block in partition role
#define NBLK_E ((N_EDGES + EPB - 1) / EPB)    // 391 partition blocks
#define GB1 ((N_NODES + 127) / 128)           // 782 GEMM1 blocks
#define CAP 1536                              // bucket capacity (mean 1024 + 16 sigma)
#define ACC_LD 132                            // acc row stride (fp32): 132%32=4 -> 2-way banks

typedef __attribute__((ext_vector_type(8))) short bf8_t;   // 8 x bf16 (4 VGPRs)
typedef __attribute__((ext_vector_type(4))) float f4_t;    // MFMA accumulator

__device__ __forceinline__ ushort f2b(float f) {           // fp32 -> bf16 RNE
    unsigned int u = __float_as_uint(f);
    u += 0x7fffu + ((u >> 16) & 1u);
    return (ushort)(u >> 16);
}
__device__ __forceinline__ float b2f_lo(unsigned int u) { return __uint_as_float(u << 16); }
__device__ __forceinline__ float b2f_hi(unsigned int u) { return __uint_as_float(u & 0xffff0000u); }

// ---- fused launch 1: partition role (blocks 0..390) + GEMM1 role (391..1172) ----
// UNCHANGED from R1 (attribution anchor). h is UNSCALED bf16.

__global__ __launch_bounds__(256, 2) void k_fuse1(const int* __restrict__ ei,
                                                  int* __restrict__ cursor,
                                                  unsigned int* __restrict__ part,
                                                  const float* __restrict__ x,
                                                  const float* __restrict__ W1,
                                                  ushort* __restrict__ h) {
    __shared__ __align__(16) ushort smem[2 * 128 * 136];   // 69632 B union
    int tid = threadIdx.x;

    if (blockIdx.x < NBLK_E) {
        // ---------- partition role ----------
        int* lh    = (int*)smem;             // local hist, then local cursor
        int* lbase = lh + NB_BUCK;           // global base of this block's run
        for (int i = tid; i < NB_BUCK; i += 256) lh[i] = 0;
        __syncthreads();
        int e0 = blockIdx.x * EPB;
        int srcv[EPB / 256], dstv[EPB / 256];
        #pragma unroll
        for (int j = 0; j < EPB / 256; j++) {
            int e = e0 + j * 256 + tid;
            if (e < N_EDGES) {
                srcv[j] = ei[e];
                dstv[j] = ei[N_EDGES + e];
                atomicAdd(&lh[dstv[j] >> BUCK_SHIFT], 1);
            } else dstv[j] = -1;
        }
        __syncthreads();
        for (int i = tid; i < NB_BUCK; i += 256) {
            int c = lh[i];
            lbase[i] = (c > 0) ? (i * CAP + atomicAdd(&cursor[i], c)) : 0;
            lh[i] = 0;                        // becomes local cursor
        }
        __syncthreads();
        #pragma unroll
        for (int j = 0; j < EPB / 256; j++) {
            if (dstv[j] >= 0) {
                int b = dstv[j] >> BUCK_SHIFT;
                int pos = lbase[b] + atomicAdd(&lh[b], 1);
                part[pos] = ((unsigned int)(dstv[j] & (BUCK_SZ - 1)) << 24) | (unsigned int)srcv[j];
            }
        }
        return;
    }

    // ---------- GEMM1 role: h = bf16(x @ W1) ----------
    typedef ushort (*tile_t)[136];
    tile_t As = (tile_t)smem;
    tile_t Bs = (tile_t)(smem + 128 * 136);
    int row0 = (blockIdx.x - NBLK_E) * 128;
    const int M = N_NODES;

    #pragma unroll
    for (int i = 0; i < 16; i++) {
        int li = tid + i * 256;
        int r = li >> 5, c4 = li & 31;
        int grow = row0 + r; if (grow > M - 1) grow = M - 1;
        float4 v = *(const float4*)(x + (size_t)grow * 128 + c4 * 4);
        ushort4 o;
        o.x = f2b(v.x); o.y = f2b(v.y); o.z = f2b(v.z); o.w = f2b(v.w);
        *(ushort4*)&As[r][c4 * 4] = o;
    }
    #pragma unroll
    for (int i = 0; i < 16; i++) {
        int li = tid + i * 256;
        int k = li >> 5, n4 = li & 31;
        float4 v = *(const float4*)(W1 + (size_t)k * 128 + n4 * 4);
        Bs[n4 * 4 + 0][k] = f2b(v.x);
        Bs[n4 * 4 + 1][k] = f2b(v.y);
        Bs[n4 * 4 + 2][k] = f2b(v.z);
        Bs[n4 * 4 + 3][k] = f2b(v.w);
    }
    __syncthreads();

    int wave = tid >> 6, lane = tid & 63;
    int lr = lane & 15, lq = lane >> 4;
    int wm0 = (wave & 1) * 64;
    int wn0 = (wave >> 1) * 64;

    f4_t acc[4][4];
    #pragma unroll
    for (int mi = 0; mi < 4; mi++)
        #pragma unroll
        for (int ni = 0; ni < 4; ni++) acc[mi][ni] = (f4_t){0.f, 0.f, 0.f, 0.f};

    #pragma unroll
    for (int kb = 0; kb < 4; kb++) {
        bf8_t af[4], bfr[4];
        #pragma unroll
        for (int mi = 0; mi < 4; mi++)
            af[mi] = *(const bf8_t*)&As[wm0 + mi * 16 + lr][kb * 32 + lq * 8];
        #pragma unroll
        for (int ni = 0; ni < 4; ni++)
            bfr[ni] = *(const bf8_t*)&Bs[wn0 + ni * 16 + lr][kb * 32 + lq * 8];
        #pragma unroll
        for (int mi = 0; mi < 4; mi++)
            #pragma unroll
            for (int ni = 0; ni < 4; ni++)
                acc[mi][ni] = __builtin_amdgcn_mfma_f32_16x16x32_bf16(
                    af[mi], bfr[ni], acc[mi][ni], 0, 0, 0);
    }

    #pragma unroll
    for (int mi = 0; mi < 4; mi++) {
        #pragma unroll
        for (int r = 0; r < 4; r++) {
            int row = row0 + wm0 + mi * 16 + lq * 4 + r;
            if (row < M) {
                #pragma unroll
                for (int ni = 0; ni < 4; ni++)
                    h[(size_t)row * 128 + wn0 + ni * 16 + lr] = f2b(acc[mi][ni][r]);
            }
        }
    }
}

// ------- k_dw: per-bucket degree hist -> dinv; pad part to x32 with sentinels;
// one extra block converts W2 to bf16 n-major and zeroes sentinels. Replaces k_csr
// (no stage/scan/reorder/scatter, no ssrc/offs/pcnt). -------

__global__ __launch_bounds__(256) void k_dw(unsigned int* __restrict__ part,
                                            const int* __restrict__ cursor,
                                            float* __restrict__ dinv,
                                            ushort* __restrict__ h,
                                            const float* __restrict__ W2,
                                            ushort* __restrict__ w2b) {
    __shared__ int ldeg[BUCK_SZ];
    int t = threadIdx.x;
    int b = blockIdx.x;
    if (b == NB_BUCK) {
        if (t == 0) dinv[N_NODES] = 0.f;                   // sentinel weight
        if (t < 128) h[(size_t)N_NODES * 128 + t] = 0;     // sentinel h row: NaN-proof
        for (int i = t; i < 128 * 64; i += 256) {          // W2[k][n] -> w2b[n][k] bf16
            int k = i >> 6, n = i & 63;
            w2b[n * 128 + k] = f2b(W2[i]);
        }
        return;
    }
    int rbeg = b * CAP;
    int cnt = cursor[b];
    int node0 = b << BUCK_SHIFT;
    if (t < BUCK_SZ) ldeg[t] = 0;
    __syncthreads();
    for (int i = t; i < cnt; i += 256)
        atomicAdd(&ldeg[part[rbeg + i] >> 24], 1);
    int total = (cnt + 31) & ~31;                          // pad: d=0, src=sentinel
    for (int i = cnt + t; i < total; i += 256)
        part[rbeg + i] = (unsigned int)N_NODES;
    __syncthreads();
    if (t < BUCK_SZ && node0 + t < N_NODES)
        dinv[node0 + t] = rsqrtf((float)(ldeg[t] + 1));    // +1: self-loop
}

// ---- k_agg2b: edge-parallel bucket accumulate + fused GEMM2 ----
// Block = one 64-node bucket. fp32 acc[64][132] in LDS (stride 132 -> 2-way banks
// on both ds_add and b128 frag reads). Waves stream part entries 8 at a time:
// SGPR indices (readfirstlane), saddr gathers, ds_add_f32 scatter. No per-node
// serialization, no CSR. Then scale/self/bias/relu in LDS and 64x128x64 MFMA
// GEMM2 with W2 read from L2-hot bf16 buffer. 33 KB LDS -> 4 blocks/CU.

__global__ __launch_bounds__(256, 4) void k_agg2b(const ushort* __restrict__ h,
                                                  const unsigned int* __restrict__ part,
                                                  const int* __restrict__ cursor,
                                                  const float* __restrict__ dinv,
                                                  const float* __restrict__ b1,
                                                  const ushort* __restrict__ w2b,
                                                  const float* __restrict__ b2,
                                                  float* __restrict__ out) {
    __shared__ __align__(16) float acc[BUCK_SZ][ACC_LD];
    int tid = threadIdx.x, wave = tid >> 6, lane = tid & 63;
    int b = blockIdx.x;
    int node0 = b << BUCK_SHIFT;

    float4* az = (float4*)&acc[0][0];
    #pragma unroll 4
    for (int i = tid; i < (BUCK_SZ * ACC_LD) / 4; i += 256) az[i] = (float4){0.f, 0.f, 0.f, 0.f};
    __syncthreads();

    const unsigned int* hp = (const unsigned int*)h;   // 2 bf16 per uint, 64/row
    int cnt = cursor[b];
    int total = (cnt + 31) & ~31;                      // k_dw guaranteed sentinel pads
    const uint4* ip = (const uint4*)(part + (size_t)b * CAP);

    int base = wave * 8;
    uint4 e0, e1;
    if (base < total) { e0 = ip[base >> 2]; e1 = ip[(base >> 2) + 1]; }
    for (; base < total; base += 32) {
        uint4 n0 = e0, n1 = e1;
        int nb = base + 32;
        if (nb < total) { n0 = ip[nb >> 2]; n1 = ip[(nb >> 2) + 1]; }
        // indices/dst wave-uniform -> SGPRs; 8 independent saddr gathers in flight
        int s0 = __builtin_amdgcn_readfirstlane((int)(e0.x & 0xFFFFFFu));
        int s1 = __builtin_amdgcn_readfirstlane((int)(e0.y & 0xFFFFFFu));
        int s2 = __builtin_amdgcn_readfirstlane((int)(e0.z & 0xFFFFFFu));
        int s3 = __builtin_amdgcn_readfirstlane((int)(e0.w & 0xFFFFFFu));
        int s4 = __builtin_amdgcn_readfirstlane((int)(e1.x & 0xFFFFFFu));
        int s5 = __builtin_amdgcn_readfirstlane((int)(e1.y & 0xFFFFFFu));
        int s6 = __builtin_amdgcn_readfirstlane((int)(e1.z & 0xFFFFFFu));
        int s7 = __builtin_amdgcn_readfirstlane((int)(e1.w & 0xFFFFFFu));
        int d0 = __builtin_amdgcn_readfirstlane((int)(e0.x >> 24));
        int d1 = __builtin_amdgcn_readfirstlane((int)(e0.y >> 24));
        int d2 = __builtin_amdgcn_readfirstlane((int)(e0.z >> 24));
        int d3 = __builtin_amdgcn_readfirstlane((int)(e0.w >> 24));
        int d4 = __builtin_amdgcn_readfirstlane((int)(e1.x >> 24));
        int d5 = __builtin_amdgcn_readfirstlane((int)(e1.y >> 24));
        int d6 = __builtin_amdgcn_readfirstlane((int)(e1.z >> 24));
        int d7 = __builtin_amdgcn_readfirstlane((int)(e1.w >> 24));
        unsigned int u0 = (hp + ((size_t)(unsigned)s0 << 6))[lane];
        unsigned int u1 = (hp + ((size_t)(unsigned)s1 << 6))[lane];
        unsigned int u2 = (hp + ((size_t)(unsigned)s2 << 6))[lane];
        unsigned int u3 = (hp + ((size_t)(unsigned)s3 << 6))[lane];
        unsigned int u4 = (hp + ((size_t)(unsigned)s4 << 6))[lane];
        unsigned int u5 = (hp + ((size_t)(unsigned)s5 << 6))[lane];
        unsigned int u6 = (hp + ((size_t)(unsigned)s6 << 6))[lane];
        unsigned int u7 = (hp + ((size_t)(unsigned)s7 << 6))[lane];
        float w0 = dinv[s0], w1 = dinv[s1], w2 = dinv[s2], w3 = dinv[s3];
        float w4 = dinv[s4], w5 = dinv[s5], w6 = dinv[s6], w7 = dinv[s7];
        float* a0 = &acc[d0][2 * lane];
        float* a1 = &acc[d1][2 * lane];
        float* a2 = &acc[d2][2 * lane];
        float* a3 = &acc[d3][2 * lane];
        float* a4 = &acc[d4][2 * lane];
        float* a5 = &acc[d5][2 * lane];
        float* a6 = &acc[d6][2 * lane];
        float* a7 = &acc[d7][2 * lane];
        atomicAdd(a0, b2f_lo(u0) * w0); atomicAdd(a0 + 1, b2f_hi(u0) * w0);
        atomicAdd(a1, b2f_lo(u1) * w1); atomicAdd(a1 + 1, b2f_hi(u1) * w1);
        atomicAdd(a2, b2f_lo(u2) * w2); atomicAdd(a2 + 1, b2f_hi(u2) * w2);
        atomicAdd(a3, b2f_lo(u3) * w3); atomicAdd(a3 + 1, b2f_hi(u3) * w3);
        atomicAdd(a4, b2f_lo(u4) * w4); atomicAdd(a4 + 1, b2f_hi(u4) * w4);
        atomicAdd(a5, b2f_lo(u5) * w5); atomicAdd(a5 + 1, b2f_hi(u5) * w5);
        atomicAdd(a6, b2f_lo(u6) * w6); atomicAdd(a6 + 1, b2f_hi(u6) * w6);
        atomicAdd(a7, b2f_lo(u7) * w7); atomicAdd(a7 + 1, b2f_hi(u7) * w7);
        e0 = n0; e1 = n1;
    }
    __syncthreads();

    // scale + self-loop + bias + relu, fp32 in place. Wave w owns rows 16w..16w+15.
    float2 bb = ((const float2*)b1)[lane];
    for (int rr = 0; rr < 16; rr++) {
        int r = wave * 16 + rr;
        int n = node0 + r;
        if (n < N_NODES) {                       // wave-uniform guard
            float dn = dinv[n];
            unsigned int us = hp[(size_t)n * 64 + lane];
            float2 a = *(float2*)&acc[r][2 * lane];
            float rx = (a.x + b2f_lo(us) * dn) * dn + bb.x;
            float ry = (a.y + b2f_hi(us) * dn) * dn + bb.y;
            rx = rx > 0.f ? rx : 0.f;
            ry = ry > 0.f ? ry : 0.f;
            *(float2*)&acc[r][2 * lane] = (float2){rx, ry};
        }
    }
    __syncthreads();

    // GEMM2: (64x128 acc -> bf16) @ W2 -> 64x64. Wave w: rows 16w..16w+15, all cols.
    int lr = lane & 15, lq = lane >> 4;
    f4_t o[4];
    #pragma unroll
    for (int nt = 0; nt < 4; nt++) o[nt] = (f4_t){0.f, 0.f, 0.f, 0.f};
    #pragma unroll
    for (int kb = 0; kb < 4; kb++) {
        const float* ar = &acc[wave * 16 + lr][kb * 32 + lq * 8];
        float4 a0 = *(const float4*)ar;
        float4 a1 = *(const float4*)(ar + 4);
        bf8_t af;
        af[0] = (short)f2b(a0.x); af[1] = (short)f2b(a0.y);
        af[2] = (short)f2b(a0.z); af[3] = (short)f2b(a0.w);
        af[4] = (short)f2b(a1.x); af[5] = (short)f2b(a1.y);
        af[6] = (short)f2b(a1.z); af[7] = (short)f2b(a1.w);
        #pragma unroll
        for (int nt = 0; nt < 4; nt++) {
            bf8_t bf = *(const bf8_t*)(w2b + (size_t)(nt * 16 + lr) * 128 + kb * 32 + lq * 8);
            o[nt] = __builtin_amdgcn_mfma_f32_16x16x32_bf16(af, bf, o[nt], 0, 0, 0);
        }
    }
    #pragma unroll
    for (int nt = 0; nt < 4; nt++) {
        int col = nt * 16 + lr;
        float bv = b2[col];
        #pragma unroll
        for (int j = 0; j < 4; j++) {
            int node = node0 + wave * 16 + lq * 4 + j;
            if (node < N_NODES)
                out[(size_t)node * 64 + col] = o[nt][j] + bv;
        }
    }
}

// ---------------- launch ----------------

extern "C" void kernel_launch(void* const* d_in, const int* in_sizes, int n_in,
                              void* d_out, int out_size, void* d_ws, size_t ws_size,
                              hipStream_t stream) {
    const float* x  = (const float*)d_in[0];
    const float* W1 = (const float*)d_in[1];
    const float* b1 = (const float*)d_in[2];
    const float* W2 = (const float*)d_in[3];
    const float* b2 = (const float*)d_in[4];
    const int*   ei = (const int*)d_in[5];
    float* out = (float*)d_out;

    char* w = (char*)d_ws;
    size_t off = 0;
    auto alloc = [&](size_t bytes) -> void* {
        void* p = w + off;
        off += (bytes + 255) & ~(size_t)255;
        return p;
    };
    ushort* h      = (ushort*)alloc((size_t)(N_NODES + 1) * HIDDEN * 2);  // +1 sentinel row
    float* dinv    = (float*)alloc((size_t)(N_NODES + 1) * 4);   // +1: dinv[N]=0 sentinel
    unsigned int* part = (unsigned int*)alloc((size_t)NB_BUCK * CAP * 4);
    int*   cursor  = (int*)alloc((size_t)NB_BUCK * 4);
    ushort* w2b    = (ushort*)alloc((size_t)OUT_DIM * HIDDEN * 2);   // W2 bf16 n-major

    hipMemsetAsync(cursor, 0, (size_t)NB_BUCK * 4, stream);
    k_fuse1<<<NBLK_E + GB1, 256, 0, stream>>>(ei, cursor, part, x, W1, h);
    k_dw<<<NB_BUCK + 1, 256, 0, stream>>>(part, cursor, dinv, h, W2, w2b);
    k_agg2b<<<NB_BUCK, 256, 0, stream>>>(h, part, cursor, dinv, b1, w2b, b2, out);
}

// Round 3
// 262.063 us; speedup vs baseline: 5.1595x; 5.1595x over previous
//
#include <hip/hip_runtime.h>

#define N_NODES 100000
#define N_EDGES 1600000
#define IN_DIM  128
#define HIDDEN  128
#define OUT_DIM 64

#define BUCK_SHIFT 6                          // 64-node buckets
#define BUCK_SZ    64
#define NB_BUCK ((N_NODES + BUCK_SZ - 1) / BUCK_SZ)   // 1563 buckets
#define EPB 4096                              // edges per block in partition/count role
#define NBLK_E ((N_EDGES + EPB - 1) / EPB)    // 391 count/scatter blocks
#define GB1 ((N_NODES + 127) / 128)           // 782 GEMM1 blocks
#define CAP 1536                              // bucket capacity (mean 1024 + 16 sigma)
#define PCAP 1984                             // padded capacity: CAP + 64*7, mult of 8
#define CSTRIDE 1600                          // counts row stride (ints), 64B-multiple

typedef __attribute__((ext_vector_type(8))) short bf8_t;   // 8 x bf16 (4 VGPRs)
typedef __attribute__((ext_vector_type(4))) float f4_t;    // MFMA accumulator

__device__ __forceinline__ ushort f2b(float f) {           // fp32 -> bf16 RNE
    unsigned int u = __float_as_uint(f);
    u += 0x7fffu + ((u >> 16) & 1u);
    return (ushort)(u >> 16);
}
__device__ __forceinline__ float b2f_lo(unsigned int u) { return __uint_as_float(u << 16); }
__device__ __forceinline__ float b2f_hi(unsigned int u) { return __uint_as_float(u & 0xffff0000u); }

// ---- k_prep: W1 -> bf16 n-major (w1b[n*128+k]); tiny, runs once ----
__global__ __launch_bounds__(256) void k_prep(const float* __restrict__ W1,
                                              ushort* __restrict__ w1b) {
    int start = blockIdx.x * 2048;
    #pragma unroll
    for (int j = 0; j < 8; j++) {
        int i = start + j * 256 + threadIdx.x;   // i = n*128 + k
        int n = i >> 7, k = i & 127;
        w1b[i] = f2b(W1[k * 128 + n]);
    }
}

// ---- k_cnt: count role (blocks 0..390) + GEMM1 role (391..1172) ----
// Count role: per-block bucket histogram -> counts[blk][bucket]. NO global atomics.
// GEMM1 role: h = bf16(x @ W1), As-only LDS (34.8KB), B fragments straight from
// L2-hot w1b. 3 blocks/CU (12 waves) vs R1's 2 blocks (8 waves).
__global__ __launch_bounds__(256, 3) void k_cnt(const int* __restrict__ ei,
                                                int* __restrict__ counts,
                                                const float* __restrict__ x,
                                                const ushort* __restrict__ w1b,
                                                ushort* __restrict__ h) {
    __shared__ __align__(16) ushort smem[128 * 136];   // 34816 B (union w/ hist)
    int tid = threadIdx.x;

    if (blockIdx.x < NBLK_E) {
        // ---------- count role ----------
        int* lh = (int*)smem;
        for (int i = tid; i < NB_BUCK; i += 256) lh[i] = 0;
        __syncthreads();
        int e0 = blockIdx.x * EPB;
        #pragma unroll
        for (int j = 0; j < EPB / 256; j++) {
            int e = e0 + j * 256 + tid;
            if (e < N_EDGES) atomicAdd(&lh[ei[N_EDGES + e] >> BUCK_SHIFT], 1);
        }
        __syncthreads();
        for (int i = tid; i < NB_BUCK; i += 256)       // coalesced row write
            counts[(size_t)blockIdx.x * CSTRIDE + i] = lh[i];
        return;
    }

    // ---------- GEMM1 role ----------
    typedef ushort (*tile_t)[136];
    tile_t As = (tile_t)smem;
    int row0 = (blockIdx.x - NBLK_E) * 128;
    const int M = N_NODES;

    #pragma unroll
    for (int i = 0; i < 16; i++) {
        int li = tid + i * 256;
        int r = li >> 5, c4 = li & 31;
        int grow = row0 + r; if (grow > M - 1) grow = M - 1;
        float4 v = *(const float4*)(x + (size_t)grow * 128 + c4 * 4);
        ushort4 o;
        o.x = f2b(v.x); o.y = f2b(v.y); o.z = f2b(v.z); o.w = f2b(v.w);
        *(ushort4*)&As[r][c4 * 4] = o;
    }
    __syncthreads();

    int wave = tid >> 6, lane = tid & 63;
    int lr = lane & 15, lq = lane >> 4;
    int wm0 = (wave & 1) * 64;
    int wn0 = (wave >> 1) * 64;

    f4_t acc[4][4];
    #pragma unroll
    for (int mi = 0; mi < 4; mi++)
        #pragma unroll
        for (int ni = 0; ni < 4; ni++) acc[mi][ni] = (f4_t){0.f, 0.f, 0.f, 0.f};

    #pragma unroll
    for (int kb = 0; kb < 4; kb++) {
        bf8_t af[4], bfr[4];
        #pragma unroll
        for (int mi = 0; mi < 4; mi++)
            af[mi] = *(const bf8_t*)&As[wm0 + mi * 16 + lr][kb * 32 + lq * 8];
        #pragma unroll
        for (int ni = 0; ni < 4; ni++)
            bfr[ni] = *(const bf8_t*)(w1b + (size_t)(wn0 + ni * 16 + lr) * 128 + kb * 32 + lq * 8);
        #pragma unroll
        for (int mi = 0; mi < 4; mi++)
            #pragma unroll
            for (int ni = 0; ni < 4; ni++)
                acc[mi][ni] = __builtin_amdgcn_mfma_f32_16x16x32_bf16(
                    af[mi], bfr[ni], acc[mi][ni], 0, 0, 0);
    }

    #pragma unroll
    for (int mi = 0; mi < 4; mi++) {
        #pragma unroll
        for (int r = 0; r < 4; r++) {
            int row = row0 + wm0 + mi * 16 + lq * 4 + r;
            if (row < M) {
                #pragma unroll
                for (int ni = 0; ni < 4; ni++)
                    h[(size_t)row * 128 + wn0 + ni * 16 + lr] = f2b(acc[mi][ni][r]);
            }
        }
    }
}

// ---- k_scan: per-bucket exclusive prefix over blocks, in place. One thread owns
// one bucket column; lanes cover consecutive buckets -> coalesced loads AND stores.
// Writes cursor[b] = bucket total. Deterministic, atomic-free. ----
__global__ __launch_bounds__(256) void k_scan(int* __restrict__ counts,
                                              int* __restrict__ cursor) {
    int b = blockIdx.x * 256 + threadIdx.x;
    if (b >= NB_BUCK) return;
    int run = b * CAP;
    #pragma unroll 8
    for (int blk = 0; blk < NBLK_E; blk++) {
        size_t idx = (size_t)blk * CSTRIDE + b;
        int c = counts[idx];
        counts[idx] = run;        // becomes base[blk][bucket]
        run += c;
    }
    cursor[b] = run - b * CAP;
}

// ---- k_part: scatter edges using LDS cursors seeded from scanned bases.
// Zero global atomics; bucket b's edges land contiguously at [b*CAP, b*CAP+cnt). ----
__global__ __launch_bounds__(256, 8) void k_part(const int* __restrict__ ei,
                                                 const int* __restrict__ counts,
                                                 unsigned int* __restrict__ part) {
    __shared__ int lcur[NB_BUCK];
    int tid = threadIdx.x, blk = blockIdx.x;
    for (int i = tid; i < NB_BUCK; i += 256)
        lcur[i] = counts[(size_t)blk * CSTRIDE + i];   // coalesced row read
    __syncthreads();
    int e0 = blk * EPB;
    #pragma unroll
    for (int j = 0; j < EPB / 256; j++) {
        int e = e0 + j * 256 + tid;
        if (e < N_EDGES) {
            int src = ei[e], dst = ei[N_EDGES + e];
            int b = dst >> BUCK_SHIFT;
            int pos = atomicAdd(&lcur[b], 1);          // LDS atomic only
            part[pos] = ((unsigned int)(dst & (BUCK_SZ - 1)) << 24) | (unsigned int)src;
        }
    }
}

// ------- k_csr: UNCHANGED from R1 (proven). Per-bucket CSR finalize. -------
__global__ __launch_bounds__(256) void k_csr(const unsigned int* __restrict__ part,
                                             const int* __restrict__ cursor,
                                             int* __restrict__ offs,
                                             int* __restrict__ pcnt,
                                             float* __restrict__ dinv,
                                             int* __restrict__ ssrc,
                                             ushort* __restrict__ h) {
    __shared__ int ldeg[BUCK_SZ], lsc[BUCK_SZ], lcur[BUCK_SZ], sob[BUCK_SZ];
    __shared__ unsigned int stage[CAP];
    int t = threadIdx.x;
    int b = blockIdx.x;
    int rbeg = b * CAP;
    int cnt = cursor[b];
    int node0 = b << BUCK_SHIFT;
    if (b == 0) {
        if (t == 0) dinv[N_NODES] = 0.f;                 // sentinel weight
        if (t < 128) h[(size_t)N_NODES * 128 + t] = 0;   // sentinel h row
    }
    if (t < BUCK_SZ) ldeg[t] = 0;
    __syncthreads();
    for (int i = t; i < cnt; i += 256) {
        unsigned int u = part[rbeg + i];
        stage[i] = u;
        atomicAdd(&ldeg[u >> 24], 1);
    }
    __syncthreads();
    int v = 0, pv = 0;
    if (t < BUCK_SZ) {
        v = ldeg[t];
        pv = (v + 7) & ~7;
        lsc[t] = pv;
    }
    __syncthreads();
    for (int off = 1; off < BUCK_SZ; off <<= 1) {
        int add = 0;
        if (t < BUCK_SZ && t >= off) add = lsc[t - off];
        __syncthreads();
        if (t < BUCK_SZ) lsc[t] += add;
        __syncthreads();
    }
    if (t < BUCK_SZ) {
        int ob = b * PCAP + (lsc[t] - pv);
        sob[t] = ob;
        lcur[t] = 0;
        if (node0 + t < N_NODES) {
            offs[node0 + t] = ob;
            pcnt[node0 + t] = pv;
            dinv[node0 + t] = rsqrtf((float)(v + 1));    // +1: self-loop
        }
    }
    __syncthreads();
    for (int i = t; i < cnt; i += 256) {
        unsigned int u = stage[i];
        int d = u >> 24;
        int pos = atomicAdd(&lcur[d], 1);
        ssrc[sob[d] + pos] = (int)(u & 0xFFFFFFu);
    }
    if (t < BUCK_SZ)
        for (int i = v; i < pv; i++) ssrc[sob[t] + i] = N_NODES;  // sentinel pads
}

// ---- k_agg2: UNCHANGED from R1 (proven 70us). Aggregation + fused GEMM2. ----
__global__ __launch_bounds__(256, 7) void k_agg2(const ushort* __restrict__ h,
                                                 const int* __restrict__ offs,
                                                 const int* __restrict__ pcnt,
                                                 const int* __restrict__ ssrc,
                                                 const float* __restrict__ dinv,
                                                 const float* __restrict__ b1,
                                                 const float* __restrict__ W2,
                                                 const float* __restrict__ b2,
                                                 float* __restrict__ out) {
    __shared__ ushort As[16][136];
    __shared__ ushort Bs[64][136];
    int tid = threadIdx.x;
    int wave = tid >> 6, lane = tid & 63;
    int base = blockIdx.x * 16;

    #pragma unroll
    for (int i = 0; i < 8; i++) {
        int li = tid + i * 256;
        int k = li >> 4, n4 = li & 15;
        float4 v = *(const float4*)(W2 + (size_t)k * 64 + n4 * 4);
        Bs[n4 * 4 + 0][k] = f2b(v.x);
        Bs[n4 * 4 + 1][k] = f2b(v.y);
        Bs[n4 * 4 + 2][k] = f2b(v.z);
        Bs[n4 * 4 + 3][k] = f2b(v.w);
    }

    const unsigned int* hp = (const unsigned int*)h;
    float2 bb = ((const float2*)b1)[lane];

    #pragma unroll 1
    for (int j = 0; j < 4; j++) {
        int r = wave * 4 + j;
        int n = base + r;
        int e0 = __builtin_amdgcn_readfirstlane(offs[n]);
        int iters = __builtin_amdgcn_readfirstlane(pcnt[n]) >> 3;
        const uint4* ip = (const uint4*)(ssrc + e0);

        float ax0 = 0.f, ay0 = 0.f, ax1 = 0.f, ay1 = 0.f;
        float ax2 = 0.f, ay2 = 0.f, ax3 = 0.f, ay3 = 0.f;
        uint4 i0, i1;
        if (iters > 0) { i0 = ip[0]; i1 = ip[1]; }
        for (int it = 0; it < iters; it++) {
            uint4 nx0 = i0, nx1 = i1;
            if (it + 1 < iters) { nx0 = ip[(it + 1) * 2]; nx1 = ip[(it + 1) * 2 + 1]; }
            int s0 = __builtin_amdgcn_readfirstlane((int)i0.x);
            int s1 = __builtin_amdgcn_readfirstlane((int)i0.y);
            int s2 = __builtin_amdgcn_readfirstlane((int)i0.z);
            int s3 = __builtin_amdgcn_readfirstlane((int)i0.w);
            int s4 = __builtin_amdgcn_readfirstlane((int)i1.x);
            int s5 = __builtin_amdgcn_readfirstlane((int)i1.y);
            int s6 = __builtin_amdgcn_readfirstlane((int)i1.z);
            int s7 = __builtin_amdgcn_readfirstlane((int)i1.w);
            unsigned int u0 = (hp + ((unsigned)s0 << 6))[lane];
            unsigned int u1 = (hp + ((unsigned)s1 << 6))[lane];
            unsigned int u2 = (hp + ((unsigned)s2 << 6))[lane];
            unsigned int u3 = (hp + ((unsigned)s3 << 6))[lane];
            unsigned int u4 = (hp + ((unsigned)s4 << 6))[lane];
            unsigned int u5 = (hp + ((unsigned)s5 << 6))[lane];
            unsigned int u6 = (hp + ((unsigned)s6 << 6))[lane];
            unsigned int u7 = (hp + ((unsigned)s7 << 6))[lane];
            float w0 = dinv[s0], w1 = dinv[s1], w2 = dinv[s2], w3 = dinv[s3];
            float w4 = dinv[s4], w5 = dinv[s5], w6 = dinv[s6], w7 = dinv[s7];
            ax0 = fmaf(b2f_lo(u0), w0, ax0); ay0 = fmaf(b2f_hi(u0), w0, ay0);
            ax1 = fmaf(b2f_lo(u1), w1, ax1); ay1 = fmaf(b2f_hi(u1), w1, ay1);
            ax2 = fmaf(b2f_lo(u2), w2, ax2); ay2 = fmaf(b2f_hi(u2), w2, ay2);
            ax3 = fmaf(b2f_lo(u3), w3, ax3); ay3 = fmaf(b2f_hi(u3), w3, ay3);
            ax0 = fmaf(b2f_lo(u4), w4, ax0); ay0 = fmaf(b2f_hi(u4), w4, ay0);
            ax1 = fmaf(b2f_lo(u5), w5, ax1); ay1 = fmaf(b2f_hi(u5), w5, ay1);
            ax2 = fmaf(b2f_lo(u6), w6, ax2); ay2 = fmaf(b2f_hi(u6), w6, ay2);
            ax3 = fmaf(b2f_lo(u7), w7, ax3); ay3 = fmaf(b2f_hi(u7), w7, ay3);
            i0 = nx0; i1 = nx1;
        }
        unsigned int us = hp[(size_t)n * 64 + lane];
        float dn = dinv[n];
        float rx = (ax0 + ax1 + ax2 + ax3 + b2f_lo(us) * dn) * dn + bb.x;
        float ry = (ay0 + ay1 + ay2 + ay3 + b2f_hi(us) * dn) * dn + bb.y;
        rx = rx > 0.f ? rx : 0.f;
        ry = ry > 0.f ? ry : 0.f;
        *(unsigned int*)&As[r][lane * 2] =
            ((unsigned int)f2b(ry) << 16) | (unsigned int)f2b(rx);
    }
    __syncthreads();

    int lr = lane & 15, lq = lane >> 4;
    f4_t acc = (f4_t){0.f, 0.f, 0.f, 0.f};
    #pragma unroll
    for (int kb = 0; kb < 4; kb++) {
        bf8_t af = *(const bf8_t*)&As[lr][kb * 32 + lq * 8];
        bf8_t bf = *(const bf8_t*)&Bs[wave * 16 + lr][kb * 32 + lq * 8];
        acc = __builtin_amdgcn_mfma_f32_16x16x32_bf16(af, bf, acc, 0, 0, 0);
    }
    int col = wave * 16 + lr;
    float bv = b2[col];
    #pragma unroll
    for (int r = 0; r < 4; r++) {
        int node = base + lq * 4 + r;
        out[(size_t)node * 64 + col] = acc[r] + bv;
    }
}

// ---------------- launch ----------------

extern "C" void kernel_launch(void* const* d_in, const int* in_sizes, int n_in,
                              void* d_out, int out_size, void* d_ws, size_t ws_size,
                              hipStream_t stream) {
    const float* x  = (const float*)d_in[0];
    const float* W1 = (const float*)d_in[1];
    const float* b1 = (const float*)d_in[2];
    const float* W2 = (const float*)d_in[3];
    const float* b2 = (const float*)d_in[4];
    const int*   ei = (const int*)d_in[5];
    float* out = (float*)d_out;

    char* w = (char*)d_ws;
    size_t off = 0;
    auto alloc = [&](size_t bytes) -> void* {
        void* p = w + off;
        off += (bytes + 255) & ~(size_t)255;
        return p;
    };
    ushort* h      = (ushort*)alloc((size_t)(N_NODES + 1) * HIDDEN * 2);  // +1 sentinel row
    float* dinv    = (float*)alloc((size_t)(N_NODES + 1) * 4);
    int*   offs    = (int*)alloc((size_t)N_NODES * 4);
    int*   pcnt    = (int*)alloc((size_t)N_NODES * 4);
    int*   ssrc    = (int*)alloc((size_t)NB_BUCK * PCAP * 4);
    unsigned int* part = (unsigned int*)alloc((size_t)NB_BUCK * CAP * 4);
    int*   cursor  = (int*)alloc((size_t)NB_BUCK * 4);
    int*   counts  = (int*)alloc((size_t)NBLK_E * CSTRIDE * 4);
    ushort* w1b    = (ushort*)alloc((size_t)HIDDEN * IN_DIM * 2);

    k_prep<<<8, 256, 0, stream>>>(W1, w1b);
    k_cnt<<<NBLK_E + GB1, 256, 0, stream>>>(ei, counts, x, w1b, h);
    k_scan<<<(NB_BUCK + 255) / 256, 256, 0, stream>>>(counts, cursor);
    k_part<<<NBLK_E, 256, 0, stream>>>(ei, counts, part);
    k_csr<<<NB_BUCK, 256, 0, stream>>>(part, cursor, offs, pcnt, dinv, ssrc, h);
    k_agg2<<<N_NODES / 16, 256, 0, stream>>>(h, offs, pcnt, ssrc, dinv, b1, W2, b2, out);
}

// Round 4
// 236.335 us; speedup vs baseline: 5.7212x; 1.1089x over previous
//
#include <hip/hip_runtime.h>

#define N_NODES 100000
#define N_EDGES 1600000
#define IN_DIM  128
#define HIDDEN  128
#define OUT_DIM 64

#define BUCK_SHIFT 6                          // 64-node buckets
#define BUCK_SZ    64
#define NB_BUCK ((N_NODES + BUCK_SZ - 1) / BUCK_SZ)   // 1563 buckets
#define EPB 4096                              // edges per block in partition/count role
#define NBLK_E ((N_EDGES + EPB - 1) / EPB)    // 391 count/scatter blocks
#define GB1 ((N_NODES + 127) / 128)           // 782 GEMM1 blocks
#define CAP 1536                              // bucket capacity (mean 1024 + 16 sigma)
#define PCAP 1984                             // padded capacity: CAP + 64*7, mult of 8
#define CSTRIDE 1600                          // counts row stride (ints), 64B-multiple

typedef __attribute__((ext_vector_type(8))) short bf8_t;   // 8 x bf16 (4 VGPRs)
typedef __attribute__((ext_vector_type(4))) float f4_t;    // MFMA accumulator

__device__ __forceinline__ ushort f2b(float f) {           // fp32 -> bf16 RNE
    unsigned int u = __float_as_uint(f);
    u += 0x7fffu + ((u >> 16) & 1u);
    return (ushort)(u >> 16);
}
__device__ __forceinline__ float b2f_lo(unsigned int u) { return __uint_as_float(u << 16); }
__device__ __forceinline__ float b2f_hi(unsigned int u) { return __uint_as_float(u & 0xffff0000u); }

// ---- k_prep: W1 -> bf16 n-major (w1b[n*128+k]); tiny, runs once ----
__global__ __launch_bounds__(256) void k_prep(const float* __restrict__ W1,
                                              ushort* __restrict__ w1b) {
    int start = blockIdx.x * 2048;
    #pragma unroll
    for (int j = 0; j < 8; j++) {
        int i = start + j * 256 + threadIdx.x;   // i = n*128 + k
        int n = i >> 7, k = i & 127;
        w1b[i] = f2b(W1[k * 128 + n]);
    }
}

// ---- k_cnt: count role (blocks 0..390) + GEMM1 role (391..1172) ----
// UNCHANGED from R3 (attribution anchor).
__global__ __launch_bounds__(256, 3) void k_cnt(const int* __restrict__ ei,
                                                int* __restrict__ counts,
                                                const float* __restrict__ x,
                                                const ushort* __restrict__ w1b,
                                                ushort* __restrict__ h) {
    __shared__ __align__(16) ushort smem[128 * 136];   // 34816 B (union w/ hist)
    int tid = threadIdx.x;

    if (blockIdx.x < NBLK_E) {
        // ---------- count role ----------
        int* lh = (int*)smem;
        for (int i = tid; i < NB_BUCK; i += 256) lh[i] = 0;
        __syncthreads();
        int e0 = blockIdx.x * EPB;
        #pragma unroll
        for (int j = 0; j < EPB / 256; j++) {
            int e = e0 + j * 256 + tid;
            if (e < N_EDGES) atomicAdd(&lh[ei[N_EDGES + e] >> BUCK_SHIFT], 1);
        }
        __syncthreads();
        for (int i = tid; i < NB_BUCK; i += 256)       // coalesced row write
            counts[(size_t)blockIdx.x * CSTRIDE + i] = lh[i];
        return;
    }

    // ---------- GEMM1 role ----------
    typedef ushort (*tile_t)[136];
    tile_t As = (tile_t)smem;
    int row0 = (blockIdx.x - NBLK_E) * 128;
    const int M = N_NODES;

    #pragma unroll
    for (int i = 0; i < 16; i++) {
        int li = tid + i * 256;
        int r = li >> 5, c4 = li & 31;
        int grow = row0 + r; if (grow > M - 1) grow = M - 1;
        float4 v = *(const float4*)(x + (size_t)grow * 128 + c4 * 4);
        ushort4 o;
        o.x = f2b(v.x); o.y = f2b(v.y); o.z = f2b(v.z); o.w = f2b(v.w);
        *(ushort4*)&As[r][c4 * 4] = o;
    }
    __syncthreads();

    int wave = tid >> 6, lane = tid & 63;
    int lr = lane & 15, lq = lane >> 4;
    int wm0 = (wave & 1) * 64;
    int wn0 = (wave >> 1) * 64;

    f4_t acc[4][4];
    #pragma unroll
    for (int mi = 0; mi < 4; mi++)
        #pragma unroll
        for (int ni = 0; ni < 4; ni++) acc[mi][ni] = (f4_t){0.f, 0.f, 0.f, 0.f};

    #pragma unroll
    for (int kb = 0; kb < 4; kb++) {
        bf8_t af[4], bfr[4];
        #pragma unroll
        for (int mi = 0; mi < 4; mi++)
            af[mi] = *(const bf8_t*)&As[wm0 + mi * 16 + lr][kb * 32 + lq * 8];
        #pragma unroll
        for (int ni = 0; ni < 4; ni++)
            bfr[ni] = *(const bf8_t*)(w1b + (size_t)(wn0 + ni * 16 + lr) * 128 + kb * 32 + lq * 8);
        #pragma unroll
        for (int mi = 0; mi < 4; mi++)
            #pragma unroll
            for (int ni = 0; ni < 4; ni++)
                acc[mi][ni] = __builtin_amdgcn_mfma_f32_16x16x32_bf16(
                    af[mi], bfr[ni], acc[mi][ni], 0, 0, 0);
    }

    #pragma unroll
    for (int mi = 0; mi < 4; mi++) {
        #pragma unroll
        for (int r = 0; r < 4; r++) {
            int row = row0 + wm0 + mi * 16 + lq * 4 + r;
            if (row < M) {
                #pragma unroll
                for (int ni = 0; ni < 4; ni++)
                    h[(size_t)row * 128 + wn0 + ni * 16 + lr] = f2b(acc[mi][ni][r]);
            }
        }
    }
}

// ---- k_scan (REWRITTEN): block-per-bucket parallel scan. Thread t owns
// counts[t][b]; 391 independent loads in flight per block (vs R3's 25-wave
// serial 391-deep walk = ~140us of exposed latency). Hillis-Steele in LDS.
// Same outputs: counts[blk][b] = b*CAP + excl_prefix; cursor[b] = total. ----
__global__ __launch_bounds__(512) void k_scan(int* __restrict__ counts,
                                              int* __restrict__ cursor) {
    __shared__ int ls[512];
    int b = blockIdx.x;           // bucket
    int t = threadIdx.x;
    int v = 0;
    if (t < NBLK_E) v = counts[(size_t)t * CSTRIDE + b];
    ls[t] = v;
    __syncthreads();
    #pragma unroll
    for (int off = 1; off < 512; off <<= 1) {
        int add = (t >= off) ? ls[t - off] : 0;
        __syncthreads();
        ls[t] += add;
        __syncthreads();
    }
    int incl = ls[t];
    if (t < NBLK_E) counts[(size_t)t * CSTRIDE + b] = b * CAP + (incl - v);
    if (t == NBLK_E - 1) cursor[b] = incl;    // bucket total
}

// ---- k_part: UNCHANGED from R3. Scatter via LDS cursors, zero global atomics. ----
__global__ __launch_bounds__(256, 8) void k_part(const int* __restrict__ ei,
                                                 const int* __restrict__ counts,
                                                 unsigned int* __restrict__ part) {
    __shared__ int lcur[NB_BUCK];
    int tid = threadIdx.x, blk = blockIdx.x;
    for (int i = tid; i < NB_BUCK; i += 256)
        lcur[i] = counts[(size_t)blk * CSTRIDE + i];   // coalesced row read
    __syncthreads();
    int e0 = blk * EPB;
    #pragma unroll
    for (int j = 0; j < EPB / 256; j++) {
        int e = e0 + j * 256 + tid;
        if (e < N_EDGES) {
            int src = ei[e], dst = ei[N_EDGES + e];
            int b = dst >> BUCK_SHIFT;
            int pos = atomicAdd(&lcur[b], 1);          // LDS atomic only
            part[pos] = ((unsigned int)(dst & (BUCK_SZ - 1)) << 24) | (unsigned int)src;
        }
    }
}

// ------- k_csr: UNCHANGED from R1 (proven). Per-bucket CSR finalize. -------
__global__ __launch_bounds__(256) void k_csr(const unsigned int* __restrict__ part,
                                             const int* __restrict__ cursor,
                                             int* __restrict__ offs,
                                             int* __restrict__ pcnt,
                                             float* __restrict__ dinv,
                                             int* __restrict__ ssrc,
                                             ushort* __restrict__ h) {
    __shared__ int ldeg[BUCK_SZ], lsc[BUCK_SZ], lcur[BUCK_SZ], sob[BUCK_SZ];
    __shared__ unsigned int stage[CAP];
    int t = threadIdx.x;
    int b = blockIdx.x;
    int rbeg = b * CAP;
    int cnt = cursor[b];
    int node0 = b << BUCK_SHIFT;
    if (b == 0) {
        if (t == 0) dinv[N_NODES] = 0.f;                 // sentinel weight
        if (t < 128) h[(size_t)N_NODES * 128 + t] = 0;   // sentinel h row
    }
    if (t < BUCK_SZ) ldeg[t] = 0;
    __syncthreads();
    for (int i = t; i < cnt; i += 256) {
        unsigned int u = part[rbeg + i];
        stage[i] = u;
        atomicAdd(&ldeg[u >> 24], 1);
    }
    __syncthreads();
    int v = 0, pv = 0;
    if (t < BUCK_SZ) {
        v = ldeg[t];
        pv = (v + 7) & ~7;
        lsc[t] = pv;
    }
    __syncthreads();
    for (int off = 1; off < BUCK_SZ; off <<= 1) {
        int add = 0;
        if (t < BUCK_SZ && t >= off) add = lsc[t - off];
        __syncthreads();
        if (t < BUCK_SZ) lsc[t] += add;
        __syncthreads();
    }
    if (t < BUCK_SZ) {
        int ob = b * PCAP + (lsc[t] - pv);
        sob[t] = ob;
        lcur[t] = 0;
        if (node0 + t < N_NODES) {
            offs[node0 + t] = ob;
            pcnt[node0 + t] = pv;
            dinv[node0 + t] = rsqrtf((float)(v + 1));    // +1: self-loop
        }
    }
    __syncthreads();
    for (int i = t; i < cnt; i += 256) {
        unsigned int u = stage[i];
        int d = u >> 24;
        int pos = atomicAdd(&lcur[d], 1);
        ssrc[sob[d] + pos] = (int)(u & 0xFFFFFFu);
    }
    if (t < BUCK_SZ)
        for (int i = v; i < pv; i++) ssrc[sob[t] + i] = N_NODES;  // sentinel pads
}

// ---- k_agg2: UNCHANGED from R1 (proven 70us). Aggregation + fused GEMM2. ----
__global__ __launch_bounds__(256, 7) void k_agg2(const ushort* __restrict__ h,
                                                 const int* __restrict__ offs,
                                                 const int* __restrict__ pcnt,
                                                 const int* __restrict__ ssrc,
                                                 const float* __restrict__ dinv,
                                                 const float* __restrict__ b1,
                                                 const float* __restrict__ W2,
                                                 const float* __restrict__ b2,
                                                 float* __restrict__ out) {
    __shared__ ushort As[16][136];
    __shared__ ushort Bs[64][136];
    int tid = threadIdx.x;
    int wave = tid >> 6, lane = tid & 63;
    int base = blockIdx.x * 16;

    #pragma unroll
    for (int i = 0; i < 8; i++) {
        int li = tid + i * 256;
        int k = li >> 4, n4 = li & 15;
        float4 v = *(const float4*)(W2 + (size_t)k * 64 + n4 * 4);
        Bs[n4 * 4 + 0][k] = f2b(v.x);
        Bs[n4 * 4 + 1][k] = f2b(v.y);
        Bs[n4 * 4 + 2][k] = f2b(v.z);
        Bs[n4 * 4 + 3][k] = f2b(v.w);
    }

    const unsigned int* hp = (const unsigned int*)h;
    float2 bb = ((const float2*)b1)[lane];

    #pragma unroll 1
    for (int j = 0; j < 4; j++) {
        int r = wave * 4 + j;
        int n = base + r;
        int e0 = __builtin_amdgcn_readfirstlane(offs[n]);
        int iters = __builtin_amdgcn_readfirstlane(pcnt[n]) >> 3;
        const uint4* ip = (const uint4*)(ssrc + e0);

        float ax0 = 0.f, ay0 = 0.f, ax1 = 0.f, ay1 = 0.f;
        float ax2 = 0.f, ay2 = 0.f, ax3 = 0.f, ay3 = 0.f;
        uint4 i0, i1;
        if (iters > 0) { i0 = ip[0]; i1 = ip[1]; }
        for (int it = 0; it < iters; it++) {
            uint4 nx0 = i0, nx1 = i1;
            if (it + 1 < iters) { nx0 = ip[(it + 1) * 2]; nx1 = ip[(it + 1) * 2 + 1]; }
            int s0 = __builtin_amdgcn_readfirstlane((int)i0.x);
            int s1 = __builtin_amdgcn_readfirstlane((int)i0.y);
            int s2 = __builtin_amdgcn_readfirstlane((int)i0.z);
            int s3 = __builtin_amdgcn_readfirstlane((int)i0.w);
            int s4 = __builtin_amdgcn_readfirstlane((int)i1.x);
            int s5 = __builtin_amdgcn_readfirstlane((int)i1.y);
            int s6 = __builtin_amdgcn_readfirstlane((int)i1.z);
            int s7 = __builtin_amdgcn_readfirstlane((int)i1.w);
            unsigned int u0 = (hp + ((unsigned)s0 << 6))[lane];
            unsigned int u1 = (hp + ((unsigned)s1 << 6))[lane];
            unsigned int u2 = (hp + ((unsigned)s2 << 6))[lane];
            unsigned int u3 = (hp + ((unsigned)s3 << 6))[lane];
            unsigned int u4 = (hp + ((unsigned)s4 << 6))[lane];
            unsigned int u5 = (hp + ((unsigned)s5 << 6))[lane];
            unsigned int u6 = (hp + ((unsigned)s6 << 6))[lane];
            unsigned int u7 = (hp + ((unsigned)s7 << 6))[lane];
            float w0 = dinv[s0], w1 = dinv[s1], w2 = dinv[s2], w3 = dinv[s3];
            float w4 = dinv[s4], w5 = dinv[s5], w6 = dinv[s6], w7 = dinv[s7];
            ax0 = fmaf(b2f_lo(u0), w0, ax0); ay0 = fmaf(b2f_hi(u0), w0, ay0);
            ax1 = fmaf(b2f_lo(u1), w1, ax1); ay1 = fmaf(b2f_hi(u1), w1, ay1);
            ax2 = fmaf(b2f_lo(u2), w2, ax2); ay2 = fmaf(b2f_hi(u2), w2, ay2);
            ax3 = fmaf(b2f_lo(u3), w3, ax3); ay3 = fmaf(b2f_hi(u3), w3, ay3);
            ax0 = fmaf(b2f_lo(u4), w4, ax0); ay0 = fmaf(b2f_hi(u4), w4, ay0);
            ax1 = fmaf(b2f_lo(u5), w5, ax1); ay1 = fmaf(b2f_hi(u5), w5, ay1);
            ax2 = fmaf(b2f_lo(u6), w6, ax2); ay2 = fmaf(b2f_hi(u6), w6, ay2);
            ax3 = fmaf(b2f_lo(u7), w7, ax3); ay3 = fmaf(b2f_hi(u7), w7, ay3);
            i0 = nx0; i1 = nx1;
        }
        unsigned int us = hp[(size_t)n * 64 + lane];
        float dn = dinv[n];
        float rx = (ax0 + ax1 + ax2 + ax3 + b2f_lo(us) * dn) * dn + bb.x;
        float ry = (ay0 + ay1 + ay2 + ay3 + b2f_hi(us) * dn) * dn + bb.y;
        rx = rx > 0.f ? rx : 0.f;
        ry = ry > 0.f ? ry : 0.f;
        *(unsigned int*)&As[r][lane * 2] =
            ((unsigned int)f2b(ry) << 16) | (unsigned int)f2b(rx);
    }
    __syncthreads();

    int lr = lane & 15, lq = lane >> 4;
    f4_t acc = (f4_t){0.f, 0.f, 0.f, 0.f};
    #pragma unroll
    for (int kb = 0; kb < 4; kb++) {
        bf8_t af = *(const bf8_t*)&As[lr][kb * 32 + lq * 8];
        bf8_t bf = *(const bf8_t*)&Bs[wave * 16 + lr][kb * 32 + lq * 8];
        acc = __builtin_amdgcn_mfma_f32_16x16x32_bf16(af, bf, acc, 0, 0, 0);
    }
    int col = wave * 16 + lr;
    float bv = b2[col];
    #pragma unroll
    for (int r = 0; r < 4; r++) {
        int node = base + lq * 4 + r;
        out[(size_t)node * 64 + col] = acc[r] + bv;
    }
}

// ---------------- launch ----------------

extern "C" void kernel_launch(void* const* d_in, const int* in_sizes, int n_in,
                              void* d_out, int out_size, void* d_ws, size_t ws_size,
                              hipStream_t stream) {
    const float* x  = (const float*)d_in[0];
    const float* W1 = (const float*)d_in[1];
    const float* b1 = (const float*)d_in[2];
    const float* W2 = (const float*)d_in[3];
    const float* b2 = (const float*)d_in[4];
    const int*   ei = (const int*)d_in[5];
    float* out = (float*)d_out;

    char* w = (char*)d_ws;
    size_t off = 0;
    auto alloc = [&](size_t bytes) -> void* {
        void* p = w + off;
        off += (bytes + 255) & ~(size_t)255;
        return p;
    };
    ushort* h      = (ushort*)alloc((size_t)(N_NODES + 1) * HIDDEN * 2);  // +1 sentinel row
    float* dinv    = (float*)alloc((size_t)(N_NODES + 1) * 4);
    int*   offs    = (int*)alloc((size_t)N_NODES * 4);
    int*   pcnt    = (int*)alloc((size_t)N_NODES * 4);
    int*   ssrc    = (int*)alloc((size_t)NB_BUCK * PCAP * 4);
    unsigned int* part = (unsigned int*)alloc((size_t)NB_BUCK * CAP * 4);
    int*   cursor  = (int*)alloc((size_t)NB_BUCK * 4);
    int*   counts  = (int*)alloc((size_t)NBLK_E * CSTRIDE * 4);
    ushort* w1b    = (ushort*)alloc((size_t)HIDDEN * IN_DIM * 2);

    k_prep<<<8, 256, 0, stream>>>(W1, w1b);
    k_cnt<<<NBLK_E + GB1, 256, 0, stream>>>(ei, counts, x, w1b, h);
    k_scan<<<NB_BUCK, 512, 0, stream>>>(counts, cursor);
    k_part<<<NBLK_E, 256, 0, stream>>>(ei, counts, part);
    k_csr<<<NB_BUCK, 256, 0, stream>>>(part, cursor, offs, pcnt, dinv, ssrc, h);
    k_agg2<<<N_NODES / 16, 256, 0, stream>>>(h, offs, pcnt, ssrc, dinv, b1, W2, b2, out);
}